// Round 17
// baseline (333.632 us; speedup 1.0000x reference)
//
#include <hip/hip_runtime.h>
#include <hip/hip_bf16.h>

#define NBATCH 8
#define NP     4096
#define ND     61
#define NK     16
#define BN     (NBATCH*NP)

// ws layout (bytes)
#define OFF_XYZT  0                          // float4 * BN       = 524288
#define OFF_IDX   (OFF_XYZT + BN*16)         // (unused now)
#define OFF_PTST  (OFF_IDX + BN*64)          // float * BN*64     = 8388608
#define OFF_BFRAG (OFF_PTST + BN*256)        // uint4 * 8192      = 131072
// total < 11272192 bytes (same budget as R2-R16 — known safe)

typedef __attribute__((ext_vector_type(8))) short bf16x8;
typedef __attribute__((ext_vector_type(4))) float f32x4;

static __device__ __forceinline__ unsigned short f2bf(float x) {
    unsigned int u = __float_as_uint(x);
    return (unsigned short)((u + 0x7fffu + ((u >> 16) & 1u)) >> 16);   // RNE
}

// merged prep: blocks 0..127 xyz-pack, 128..639 points-transpose, 640..671 bfrag
__global__ __launch_bounds__(256) void k_prep(const float* __restrict__ xyz,
                                              const float* __restrict__ pts,
                                              const float* __restrict__ lw,
                                              float4* __restrict__ xyzt,
                                              float* __restrict__ ptst,
                                              uint4* __restrict__ bfrag) {
#pragma clang fp contract(off)
    __shared__ float tile[64][65];
    int blk = blockIdx.x;
    int tid = threadIdx.x;
    if (blk < 128) {
        int t = blk * 256 + tid;             // 0..BN-1
        int b = t >> 12, n = t & (NP - 1);
        const float* base = xyz + (size_t)b * 3 * NP + n;
        float x = base[0], y = base[NP], z = base[2 * NP];
        // match numpy: sum(xyz*xyz,-1) = ((x*x + y*y) + z*z), no FMA fusion
        float sq = ((x * x) + (y * y)) + (z * z);
        xyzt[t] = make_float4(x, y, z, sq);
    } else if (blk < 640) {
        int bb = blk - 128;                  // 512 transpose blocks
        int b = bb >> 6; int n0 = (bb & 63) << 6;
        int rg = tid >> 6; int cl = tid & 63;
#pragma unroll
        for (int d0 = 0; d0 < 64; d0 += 4) {
            int d = d0 + rg;
            if (d < ND) tile[d][cl] = pts[((size_t)b * ND + d) * NP + n0 + cl];
        }
        __syncthreads();
#pragma unroll
        for (int r = 0; r < 16; ++r) {
            int n1 = r * 4 + rg;
            float v = (cl < ND) ? tile[cl][n1] : 0.0f;
            ptst[((size_t)b * NP + n0 + n1) * 64 + cl] = v;
        }
    } else {
        int e = (blk - 640) * 256 + tid;     // 0..8191
        int lane = e & 63, nt = (e >> 6) & 3, ks = e >> 8;
        int k0 = ks * 32 + (lane >> 4) * 8;
        int n = nt * 16 + (lane & 15);
        const float* src = lw + (size_t)n * 1024 + k0;
        unsigned int pk[4];
#pragma unroll
        for (int i = 0; i < 4; ++i)
            pk[i] = ((unsigned int)f2bf(src[2 * i + 1]) << 16) | f2bf(src[2 * i]);
        bfrag[e] = make_uint4(pk[0], pk[1], pk[2], pk[3]);
    }
}

#define INSERT16(dv, jv)                                            \
    do {                                                            \
        bd[15] = (dv); bi[15] = (jv);                               \
        _Pragma("unroll")                                           \
        for (int s_ = 15; s_ > 0; --s_) {                           \
            bool sw_ = bd[s_] < bd[s_ - 1];                         \
            float td_ = bd[s_]; int ti_ = bi[s_];                   \
            bd[s_]     = sw_ ? bd[s_ - 1] : td_;                    \
            bi[s_]     = sw_ ? bi[s_ - 1] : ti_;                    \
            bd[s_ - 1] = sw_ ? td_ : bd[s_ - 1];                    \
            bi[s_ - 1] = sw_ ? ti_ : bi[s_ - 1];                    \
        }                                                           \
    } while (0)

#define DRAIN16(basev)                                                        \
    do {                                                                      \
        for (int r_ = 0; r_ < 16; ++r_) {                                     \
            if (!__any(r_ < cnt)) break;                                      \
            if (r_ < cnt) {                                                   \
                int loc_ = ring[r_ * 64 + lane];                              \
                float4 cd_ = tile[loc_];                                      \
                float dot_ = __fadd_rn(__fadd_rn(__fmul_rn(cd_.x, me.x),      \
                                                 __fmul_rn(cd_.y, me.y)),     \
                                       __fmul_rn(cd_.z, me.z));               \
                float dist_ = __fsub_rn(__fadd_rn(me.w, cd_.w),               \
                                        __fmul_rn(2.0f, dot_));               \
                if (dist_ < bd[15]) {                                         \
                    int gj_ = (basev) + loc_;                                 \
                    INSERT16(dist_, gj_);                                     \
                }                                                             \
            }                                                                 \
        }                                                                     \
        cnt = 0;                                                              \
        T = fminf(T, (bd[15] - me.w) + 1.0e-3f);                              \
    } while (0)

#define TSYNC()                                                               \
    do {                                                                      \
        Tsh[w * 64 + lane] = bd[15];                                          \
        float tm_ = Tsh[lane];                                                \
        _Pragma("unroll")                                                     \
        for (int v_ = 1; v_ < 8; ++v_) tm_ = fminf(tm_, Tsh[v_ * 64 + lane]); \
        T = fminf(T, (tm_ - me.w) + 1.0e-3f);                                 \
    } while (0)

// Fused knn + wagg: 512 blocks x 512 thr. Per block: R16 knn (scan + ordered
// two-stage merge) -> per-query top-16 to LDS idxL (u16) -> 4x16-point wagg
// chunks (WeightNet + agg + MFMA linear + LeakyReLU), math bit-identical to
// R16's k_wagg. Removes the inter-kernel barrier: one block's wagg overlaps
// other blocks' knn scans. LDS 54272B -> 3 blocks/CU cap; grid needs 2/CU.
__global__ __launch_bounds__(512, 4) void k_fused(
    const float4* __restrict__ xyzt, const float* __restrict__ ptst,
    const uint4* __restrict__ bfrag,
    const float* __restrict__ w0, const float* __restrict__ b0,
    const float* __restrict__ w1, const float* __restrict__ b1,
    const float* __restrict__ w2, const float* __restrict__ b2,
    const float* __restrict__ linb, float* __restrict__ out) {
    __shared__ char smem[54272];
    int tid = threadIdx.x;
    int blk = blockIdx.x;               // 512
    int w = tid >> 6, lane = tid & 63;
    int b = blk >> 6;
    int qbase = (blk & 63) << 6;
    const float4* xb = xyzt + (size_t)b * NP;
    size_t bN = (size_t)b * NP;
    unsigned short* idxL = (unsigned short*)(smem + 52224);  // [64][16] u16, persists

    // ================= knn part (R16 verbatim) =================
    {
        float4* tile = (float4*)(smem + w * 4096);                        // 256 f4/wave
        unsigned short* ring = (unsigned short*)(smem + 32768 + w * 2048);// [16][64] u16
        float* Tsh = (float*)(smem + 49152);                              // [8][64]

        float4 me = xb[qbase + lane];
        float bd[16]; int bi[16];
#pragma unroll
        for (int i = 0; i < 16; ++i) { bd[i] = 3.0e38f; bi[i] = 0; }
        int cnt = 0;
        float T = 3.0e38f;              // filter threshold (on df = dist - me.w)
        Tsh[w * 64 + lane] = 3.0e38f;
        __syncthreads();                // Tsh init visible before any TSYNC read

        int cbase = w * 512;
        for (int half = 0; half < 2; ++half) {
            int base = cbase + half * 256;
#pragma unroll
            for (int r = 0; r < 4; ++r)
                tile[lane + r * 64] = xb[base + lane + r * 64];
            // wave-private tile: compiler inserts lgkm waits, no barrier needed
            for (int seg = 0; seg < 4; ++seg) {
                for (int g = 0; g < 8; ++g) {
                    int j0 = seg * 64 + g * 8;
#pragma unroll
                    for (int u = 0; u < 8; ++u) {
                        int jj = j0 + u;
                        float4 cd = tile[jj];
                        float dotf = fmaf(cd.z, me.z, fmaf(cd.y, me.y, cd.x * me.x));
                        float df = fmaf(-2.0f, dotf, cd.w);
                        ring[cnt * 64 + lane] = (unsigned short)jj;  // branchless
                        cnt += (df < T) ? 1 : 0;
                    }
                    if (__any(cnt >= 8)) { DRAIN16(base); }
                    if (half == 0 && seg == 0 && (g == 1 || g == 3)) { TSYNC(); }
                }
                TSYNC();                // every 64 candidates
            }
            DRAIN16(base);              // flush before tile overwrite
        }

        // two-stage s-ASCENDING merge (tie order load-bearing, R13 lesson)
        __syncthreads();
        float2* part = (float2*)smem;   // [4][16][64] float2 = 32KB overlay
        if (w < 4) {
#pragma unroll
            for (int e = 0; e < 16; ++e)
                part[(w * 16 + e) * 64 + lane] = make_float2(bd[e], __int_as_float(bi[e]));
        }
        __syncthreads();
        if (w == 0) {
            for (int s = 1; s < 4; ++s) {
#pragma unroll
                for (int e = 0; e < 16; ++e) {
                    float2 v = part[(s * 16 + e) * 64 + lane];
                    if (v.x >= bd[15]) break;
                    float d_ = v.x; int j_ = __float_as_int(v.y);
                    INSERT16(d_, j_);
                }
            }
        }
        __syncthreads();
        if (w >= 4) {
#pragma unroll
            for (int e = 0; e < 16; ++e)
                part[((w - 4) * 16 + e) * 64 + lane] = make_float2(bd[e], __int_as_float(bi[e]));
        }
        __syncthreads();
        if (w == 0) {                   // merge s=4..7 ascending; publish to idxL
            for (int s = 0; s < 4; ++s) {
#pragma unroll
                for (int e = 0; e < 16; ++e) {
                    float2 v = part[(s * 16 + e) * 64 + lane];
                    if (v.x >= bd[15]) break;
                    float d_ = v.x; int j_ = __float_as_int(v.y);
                    INSERT16(d_, j_);
                }
            }
#pragma unroll
            for (int e = 0; e < 16; ++e)
                idxL[lane * 16 + e] = (unsigned short)bi[e];   // batch-local < 4096
        }
    }
    __syncthreads();                    // idxL ready; knn scratch dead

    // ================= wagg part: 4 chunks of 16 points =================
    float* wkl  = (float*)smem;                 // [256*16] fp32 16KB (swizzled)
    float* relx = (float*)(smem + 16384);       // [256]
    float* rely = (float*)(smem + 17408);
    float* relz = (float*)(smem + 18432);
    char*  aggL = smem + 19456;                 // 32KB bf16 A-tile [16p][1024k]

    for (int c = 0; c < 4; ++c) {
        int n0 = qbase + c * 16;                // batch-local col base

        // ---- phase 1: WeightNet (threads 0..255, mapping identical to k_wagg)
        if (tid < 256) {
            int pw = lane >> 4, k = lane & 15;
            int p = (tid >> 6) * 4 + pw;
            int r = p * 16 + k;
            int j = idxL[(c * 16 + p) * 16 + k];
            float4 pj = xb[j];
            float4 pq = xb[n0 + p];
            float rx = pj.x - pq.x, ry = pj.y - pq.y, rz = pj.z - pq.z;
            float h0[8], h1[8], wv[16];
#pragma unroll
            for (int o = 0; o < 8; ++o) {
                float a = w0[o * 3 + 0] * rx + w0[o * 3 + 1] * ry + w0[o * 3 + 2] * rz + b0[o];
                h0[o] = a > 0.0f ? a : 0.0f;
            }
#pragma unroll
            for (int o = 0; o < 8; ++o) {
                float a = b1[o];
#pragma unroll
                for (int c2 = 0; c2 < 8; ++c2) a += w1[o * 8 + c2] * h0[c2];
                h1[o] = a > 0.0f ? a : 0.0f;
            }
#pragma unroll
            for (int o = 0; o < 16; ++o) {
                float a = b2[o];
#pragma unroll
                for (int c2 = 0; c2 < 8; ++c2) a += w2[o * 8 + c2] * h1[c2];
                wv[o] = a > 0.0f ? a : 0.0f;
            }
            int f = (r >> 1) & 3;
#pragma unroll
            for (int s = 0; s < 4; ++s)
                *(float4*)&wkl[r * 16 + ((s ^ f) << 2)] =
                    make_float4(wv[s * 4], wv[s * 4 + 1], wv[s * 4 + 2], wv[s * 4 + 3]);
            relx[r] = rx; rely[r] = ry; relz[r] = rz;
        }
        __syncthreads();

        // ---- phase 2: 8 waves x 2 points; gathers hoisted 8-deep; FMA order
        //      k-ascending (bit-identical to k_wagg)
        for (int u = 0; u < 2; ++u) {
            int p = w * 2 + u;
            float acc[16];
#pragma unroll
            for (int q = 0; q < 16; ++q) acc[q] = 0.0f;
#pragma unroll
            for (int kh = 0; kh < 2; ++kh) {
                float vv[8];
#pragma unroll
                for (int kk = 0; kk < 8; ++kk) {
                    int r = p * 16 + kh * 8 + kk;
                    int j = idxL[(c * 16 + p) * 16 + kh * 8 + kk];
                    vv[kk] = (lane >= 3) ? ptst[(bN + j) * 64 + (lane - 3)]
                                         : ((lane == 0) ? relx[r]
                                                        : ((lane == 1) ? rely[r] : relz[r]));
                }
#pragma unroll
                for (int kk = 0; kk < 8; ++kk) {
                    int r = p * 16 + kh * 8 + kk;
                    int f = (r >> 1) & 3;
                    float v = vv[kk];
#pragma unroll
                    for (int s = 0; s < 4; ++s) {
                        float4 wv4 = *(const float4*)&wkl[r * 16 + ((s ^ f) << 2)];
                        acc[s * 4 + 0] = fmaf(v, wv4.x, acc[s * 4 + 0]);
                        acc[s * 4 + 1] = fmaf(v, wv4.y, acc[s * 4 + 1]);
                        acc[s * 4 + 2] = fmaf(v, wv4.z, acc[s * 4 + 2]);
                        acc[s * 4 + 3] = fmaf(v, wv4.w, acc[s * 4 + 3]);
                    }
                }
            }
            unsigned int pk[8];
#pragma unroll
            for (int i = 0; i < 8; ++i)
                pk[i] = ((unsigned int)f2bf(acc[2 * i + 1]) << 16) | f2bf(acc[2 * i]);
            int cx = lane ^ (p & 7);
            *(uint4*)&aggL[p * 2048 + cx * 16]        = make_uint4(pk[0], pk[1], pk[2], pk[3]);
            *(uint4*)&aggL[p * 2048 + 1024 + cx * 16] = make_uint4(pk[4], pk[5], pk[6], pk[7]);
        }
        __syncthreads();

        // ---- phase 3: MFMA over K=1024 (waves 0..3, verbatim)
        f32x4 cacc = {0.0f, 0.0f, 0.0f, 0.0f};
        if (w < 4) {
            int p_ = lane & 15, oct = lane >> 4;
            int h = oct & 1, chalf = oct >> 1;
            int pbase = p_ * 2048 + h * 1024;
            int px = p_ & 7;
#pragma unroll 4
            for (int ks = 0; ks < 32; ++ks) {
                int cc = ks * 2 + chalf;
                bf16x8 av = *(const bf16x8*)&aggL[pbase + ((cc ^ px) << 4)];
                bf16x8 bv = *(const bf16x8*)&bfrag[(ks * 4 + w) * 64 + lane];
                cacc = __builtin_amdgcn_mfma_f32_16x16x32_bf16(av, bv, cacc, 0, 0, 0);
            }
        }
        __syncthreads();                // wkl dead -> reuse for C transpose
        float* cout = wkl;              // [64 o][17 p]
        if (w < 4) {
            int o = w * 16 + (lane & 15);
            int rbase = (lane >> 4) * 4;    // C/D row = (lane>>4)*4 + reg [m89]
#pragma unroll
            for (int reg = 0; reg < 4; ++reg)
                cout[o * 17 + rbase + reg] = cacc[reg];
        }
        __syncthreads();
        if (tid < 256) {
            int oo = tid >> 2, pq = tid & 3;
            float bias = linb[oo];
            float res[4];
#pragma unroll
            for (int e = 0; e < 4; ++e) {
                float s = cout[oo * 17 + pq * 4 + e] + bias;
                res[e] = s > 0.0f ? s : 0.1f * s;
            }
            *(float4*)&out[((size_t)(b * 64 + oo)) * NP + n0 + pq * 4] =
                make_float4(res[0], res[1], res[2], res[3]);
        }
        __syncthreads();                // protect wkl/cout before next chunk
    }
}

extern "C" void kernel_launch(void* const* d_in, const int* in_sizes, int n_in,
                              void* d_out, int out_size, void* d_ws, size_t ws_size,
                              hipStream_t stream) {
    const float* xyz  = (const float*)d_in[0];
    const float* pts  = (const float*)d_in[1];
    const float* w0   = (const float*)d_in[2];
    const float* b0   = (const float*)d_in[3];
    const float* w1   = (const float*)d_in[4];
    const float* b1   = (const float*)d_in[5];
    const float* w2   = (const float*)d_in[6];
    const float* b2   = (const float*)d_in[7];
    const float* lw   = (const float*)d_in[8];
    const float* linb = (const float*)d_in[9];
    float* out = (float*)d_out;

    char* ws = (char*)d_ws;
    float4* xyzt  = (float4*)(ws + OFF_XYZT);
    float*  ptst  = (float*)(ws + OFF_PTST);
    uint4*  bfrag = (uint4*)(ws + OFF_BFRAG);

    k_prep<<<672, 256, 0, stream>>>(xyz, pts, lw, xyzt, ptst, bfrag);
    k_fused<<<512, 512, 0, stream>>>(xyzt, ptst, bfrag,
                                     w0, b0, w1, b1, w2, b2, linb, out);
    (void)in_sizes; (void)n_in; (void)out_size; (void)ws_size;
}

// Round 18
// 217.244 us; speedup vs baseline: 1.5357x; 1.5357x over previous
//
#include <hip/hip_runtime.h>
#include <hip/hip_bf16.h>

#define NBATCH 8
#define NP     4096
#define ND     61
#define NK     16
#define BN     (NBATCH*NP)

// ws layout (bytes)
#define OFF_XYZT  0                          // float4 * BN       = 524288
#define OFF_IDX   (OFF_XYZT + BN*16)         // int * BN*16       = 2097152
#define OFF_PTST  (OFF_IDX + BN*64)          // float * BN*64     = 8388608
#define OFF_BFRAG (OFF_PTST + BN*256)        // uint4 * 8192      = 131072
// total < 11272192 bytes (same budget as R2-R17 — known safe)

typedef __attribute__((ext_vector_type(8))) short bf16x8;
typedef __attribute__((ext_vector_type(4))) float f32x4;

static __device__ __forceinline__ unsigned short f2bf(float x) {
    unsigned int u = __float_as_uint(x);
    return (unsigned short)((u + 0x7fffu + ((u >> 16) & 1u)) >> 16);   // RNE
}

// xyz pack (must precede knn): match numpy op-order, no FMA fusion
__global__ __launch_bounds__(256) void k_prep_xyz(const float* __restrict__ xyz,
                                                  float4* __restrict__ xyzt) {
#pragma clang fp contract(off)
    int t = blockIdx.x * 256 + threadIdx.x;      // 0..BN-1
    int b = t >> 12, n = t & (NP - 1);
    const float* base = xyz + (size_t)b * 3 * NP + n;
    float x = base[0], y = base[NP], z = base[2 * NP];
    float sq = ((x * x) + (y * y)) + (z * z);
    xyzt[t] = make_float4(x, y, z, sq);
}

#define INSERT16(dv, jv)                                            \
    do {                                                            \
        bd[15] = (dv); bi[15] = (jv);                               \
        _Pragma("unroll")                                           \
        for (int s_ = 15; s_ > 0; --s_) {                           \
            bool sw_ = bd[s_] < bd[s_ - 1];                         \
            float td_ = bd[s_]; int ti_ = bi[s_];                   \
            bd[s_]     = sw_ ? bd[s_ - 1] : td_;                    \
            bi[s_]     = sw_ ? bi[s_ - 1] : ti_;                    \
            bd[s_ - 1] = sw_ ? td_ : bd[s_ - 1];                    \
            bi[s_ - 1] = sw_ ? ti_ : bi[s_ - 1];                    \
        }                                                           \
    } while (0)

// Drain the u16 idx-ring (tile-local idx): recompute EXACT (numpy op-order)
// distance from the LDS tile via _rn intrinsics, strict-< check, insert.
#define DRAIN16(basev)                                                        \
    do {                                                                      \
        for (int r_ = 0; r_ < 16; ++r_) {                                     \
            if (!__any(r_ < cnt)) break;                                      \
            if (r_ < cnt) {                                                   \
                int loc_ = ring[r_ * 64 + lane];                              \
                float4 cd_ = tile[loc_];                                      \
                float dot_ = __fadd_rn(__fadd_rn(__fmul_rn(cd_.x, me.x),      \
                                                 __fmul_rn(cd_.y, me.y)),     \
                                       __fmul_rn(cd_.z, me.z));               \
                float dist_ = __fsub_rn(__fadd_rn(me.w, cd_.w),               \
                                        __fmul_rn(2.0f, dot_));               \
                if (dist_ < bd[15]) {                                         \
                    int gj_ = (basev) + loc_;                                 \
                    INSERT16(dist_, gj_);                                     \
                }                                                             \
            }                                                                 \
        }                                                                     \
        cnt = 0;                                                              \
        T = fminf(T, (bd[15] - me.w) + 1.0e-3f);                              \
    } while (0)

// share thresholds across the 8 waves (all serve the same 64 queries):
// T can only tighten toward (global d16 + margin); stale reads are looser->safe
#define TSYNC()                                                               \
    do {                                                                      \
        Tsh[w * 64 + lane] = bd[15];                                          \
        float tm_ = Tsh[lane];                                                \
        _Pragma("unroll")                                                     \
        for (int v_ = 1; v_ < 8; ++v_) tm_ = fminf(tm_, Tsh[v_ * 64 + lane]); \
        T = fminf(T, (tm_ - me.w) + 1.0e-3f);                                 \
    } while (0)

// Combined launch: blocks 0..511 = knn; 512..767 = points-transpose;
// 768..783 = bfrag (ptst/bfrag only consumed by k_wagg -> run in knn's shadow).
// knn scan uses BRANCHLESS ring push: unconditional u16 write + predicated
// cnt increment (slots >= cnt are garbage, never read; overwritten next pass).
__global__ __launch_bounds__(512) void k_knn(const float4* __restrict__ xyzt,
                                             int* __restrict__ out,
                                             const float* __restrict__ pts,
                                             const float* __restrict__ lw,
                                             float* __restrict__ ptst,
                                             uint4* __restrict__ bfrag) {
    __shared__ char smem[51200];
    int tid = threadIdx.x;
    int blk = blockIdx.x;

    if (blk >= 512) {
        if (blk < 768) {
            // ---- points-transpose: 2 tiles per block ----
            int tl = tid >> 8, ltid = tid & 255;
            int t = (blk - 512) * 2 + tl;        // tile id 0..511
            int b = t >> 6; int n0 = (t & 63) << 6;
            int rg = ltid >> 6; int cl = ltid & 63;
            float* tileT = (float*)smem + tl * (64 * 65);  // 2 x 16.6KB < 50KB
#pragma unroll
            for (int d0 = 0; d0 < 64; d0 += 4) {
                int d = d0 + rg;
                if (d < ND) tileT[d * 65 + cl] = pts[((size_t)b * ND + d) * NP + n0 + cl];
            }
            __syncthreads();
#pragma unroll
            for (int r = 0; r < 16; ++r) {
                int n1 = r * 4 + rg;
                float v = (cl < ND) ? tileT[cl * 65 + n1] : 0.0f;
                ptst[((size_t)b * NP + n0 + n1) * 64 + cl] = v;
            }
        } else {
            // ---- bfrag: B[k][n] = lin_w[n][k] -> bf16 MFMA fragments ----
            int e = (blk - 768) * 512 + tid;     // 0..8191
            int lane = e & 63, nt = (e >> 6) & 3, ks = e >> 8;
            int k0 = ks * 32 + (lane >> 4) * 8;
            int n = nt * 16 + (lane & 15);
            const float* src = lw + (size_t)n * 1024 + k0;
            unsigned int pk[4];
#pragma unroll
            for (int i = 0; i < 4; ++i)
                pk[i] = ((unsigned int)f2bf(src[2 * i + 1]) << 16) | f2bf(src[2 * i]);
            bfrag[e] = make_uint4(pk[0], pk[1], pk[2], pk[3]);
        }
        return;
    }

    // ---------------- knn branch ----------------
    int w = tid >> 6, lane = tid & 63;
    int b = blk >> 6;
    int qbase = (blk & 63) << 6;
    const float4* xb = xyzt + (size_t)b * NP;

    float4* tile = (float4*)(smem + w * 4096);                        // 256 f4/wave
    unsigned short* ring = (unsigned short*)(smem + 32768 + w * 2048);// [16][64] u16
    float* Tsh = (float*)(smem + 49152);                              // [8][64]

    float4 me = xb[qbase + lane];
    float bd[16]; int bi[16];
#pragma unroll
    for (int i = 0; i < 16; ++i) { bd[i] = 3.0e38f; bi[i] = 0; }
    int cnt = 0;
    float T = 3.0e38f;                  // filter threshold (on df = dist - me.w)
    Tsh[w * 64 + lane] = 3.0e38f;
    __syncthreads();                    // Tsh init visible before any TSYNC read

    int cbase = w * 512;
    for (int half = 0; half < 2; ++half) {
        int base = cbase + half * 256;
#pragma unroll
        for (int r = 0; r < 4; ++r)
            tile[lane + r * 64] = xb[base + lane + r * 64];
        // wave-private tile: compiler inserts lgkm waits, no barrier needed
        for (int seg = 0; seg < 4; ++seg) {
            for (int g = 0; g < 8; ++g) {
                int j0 = seg * 64 + g * 8;
#pragma unroll
                for (int u = 0; u < 8; ++u) {
                    int jj = j0 + u;
                    float4 cd = tile[jj];
                    // fused filter: df = cd.w - 2*dot vs T = d16bound - me.w + m
                    float dotf = fmaf(cd.z, me.z, fmaf(cd.y, me.y, cd.x * me.x));
                    float df = fmaf(-2.0f, dotf, cd.w);
                    // branchless push: unconditional write, predicated count
                    ring[cnt * 64 + lane] = (unsigned short)jj;
                    cnt += (df < T) ? 1 : 0;
                }
                if (__any(cnt >= 8)) { DRAIN16(base); }
                if (half == 0 && seg == 0 && (g == 1 || g == 3)) { TSYNC(); }
            }
            TSYNC();                    // every 64 candidates
        }
        DRAIN16(base);                  // flush before tile overwrite
    }

    // ---- two-stage ordered merge (preserves s-ascending insertion order;
    //      R13 proved exact-f32 boundary ties exist -> order is load-bearing) ----
    __syncthreads();                    // rings/tiles dead; part overlay begins
    float2* part = (float2*)smem;       // [4][16][64] float2 = 32KB overlay
    if (w < 4) {
#pragma unroll
        for (int e = 0; e < 16; ++e)
            part[(w * 16 + e) * 64 + lane] = make_float2(bd[e], __int_as_float(bi[e]));
    }
    __syncthreads();
    if (w == 0) {                       // merge s=1..3 into own regs
        for (int s = 1; s < 4; ++s) {
#pragma unroll
            for (int e = 0; e < 16; ++e) {
                float2 v = part[(s * 16 + e) * 64 + lane];
                if (v.x >= bd[15]) break;
                float d_ = v.x; int j_ = __float_as_int(v.y);
                INSERT16(d_, j_);
            }
        }
    }
    __syncthreads();
    if (w >= 4) {
#pragma unroll
        for (int e = 0; e < 16; ++e)
            part[((w - 4) * 16 + e) * 64 + lane] = make_float2(bd[e], __int_as_float(bi[e]));
    }
    __syncthreads();
    if (w == 0) {                       // merge s=4..7 (ascending), then store
        for (int s = 0; s < 4; ++s) {
#pragma unroll
            for (int e = 0; e < 16; ++e) {
                float2 v = part[(s * 16 + e) * 64 + lane];
                if (v.x >= bd[15]) break;
                float d_ = v.x; int j_ = __float_as_int(v.y);
                INSERT16(d_, j_);
            }
        }
        int4* op = (int4*)(out + ((size_t)b * NP + qbase + lane) * 16);
        op[0] = make_int4(bi[0], bi[1], bi[2], bi[3]);
        op[1] = make_int4(bi[4], bi[5], bi[6], bi[7]);
        op[2] = make_int4(bi[8], bi[9], bi[10], bi[11]);
        op[3] = make_int4(bi[12], bi[13], bi[14], bi[15]);
    }
}

// WeightNet + aggregation (vector) + final linear via MFMA + LeakyReLU.
// block = 256 threads (4 waves), 16 points per block.
// Phase 2 gathers: ALL 16 k-gathers of a u-iteration issued back-to-back
// (16 outstanding loads) before the FMA block; k-ascending FMA order kept
// (bit-identical output).
__global__ __launch_bounds__(256) void k_wagg(
    const float4* __restrict__ xyzt, const int* __restrict__ knn,
    const float* __restrict__ ptst, const uint4* __restrict__ bfrag,
    const float* __restrict__ w0, const float* __restrict__ b0,
    const float* __restrict__ w1, const float* __restrict__ b1,
    const float* __restrict__ w2, const float* __restrict__ b2,
    const float* __restrict__ linb, float* __restrict__ out) {
    __shared__ float wkl[256 * 16];    // 16KB weightnet outputs (fp32, swizzled)
    __shared__ float4 rel4[256];       // 4KB  rel coords + neighbor idx
    __shared__ uint4 aggL4[16 * 128];  // 32KB bf16 A-tile [16 p][1024 k], swizzled
    char* aggL = (char*)aggL4;

    int tid = threadIdx.x;
    int wid = tid >> 6, lane = tid & 63;
    int q0 = blockIdx.x * 16;          // global point base
    int b = q0 >> 12;
    int n0 = q0 & (NP - 1);
    size_t bN = (size_t)b * NP;

    // ---------------- phase 1: WeightNet, all 16 points x 16 neighbors
    {
        int pw = lane >> 4, k = lane & 15;
        int p = wid * 4 + pw;
        int r = p * 16 + k;
        int q = q0 + p;
        int j = knn[(size_t)q * 16 + k];
        float4 pj = xyzt[bN + j];
        float4 pq = xyzt[q];
        float rx = pj.x - pq.x, ry = pj.y - pq.y, rz = pj.z - pq.z;
        float h0[8], h1[8], wv[16];
#pragma unroll
        for (int o = 0; o < 8; ++o) {
            float a = w0[o * 3 + 0] * rx + w0[o * 3 + 1] * ry + w0[o * 3 + 2] * rz + b0[o];
            h0[o] = a > 0.0f ? a : 0.0f;
        }
#pragma unroll
        for (int o = 0; o < 8; ++o) {
            float a = b1[o];
#pragma unroll
            for (int c2 = 0; c2 < 8; ++c2) a += w1[o * 8 + c2] * h0[c2];
            h1[o] = a > 0.0f ? a : 0.0f;
        }
#pragma unroll
        for (int o = 0; o < 16; ++o) {
            float a = b2[o];
#pragma unroll
            for (int c2 = 0; c2 < 8; ++c2) a += w2[o * 8 + c2] * h1[c2];
            wv[o] = a > 0.0f ? a : 0.0f;
        }
        int f = (r >> 1) & 3;
#pragma unroll
        for (int s = 0; s < 4; ++s)
            *(float4*)&wkl[r * 16 + ((s ^ f) << 2)] =
                make_float4(wv[s * 4], wv[s * 4 + 1], wv[s * 4 + 2], wv[s * 4 + 3]);
        rel4[r] = make_float4(rx, ry, rz, __int_as_float(j));
    }
    __syncthreads();

    // ------------ phase 2: agg rows in registers -> bf16 A-tile in LDS
    for (int u = 0; u < 4; ++u) {
        int p = wid * 4 + u;
        float acc[16];
#pragma unroll
        for (int w = 0; w < 16; ++w) acc[w] = 0.0f;
        float vv[16];
#pragma unroll
        for (int kk = 0; kk < 16; ++kk) {          // 16 independent gathers
            int r = p * 16 + kk;
            float4 rj = rel4[r];
            int j = __float_as_int(rj.w);
            vv[kk] = (lane >= 3) ? ptst[(bN + j) * 64 + (lane - 3)]
                                 : ((lane == 0) ? rj.x : ((lane == 1) ? rj.y : rj.z));
        }
#pragma unroll
        for (int kk = 0; kk < 16; ++kk) {          // FMAs, k-ascending (same order)
            int r = p * 16 + kk;
            int f = (r >> 1) & 3;
            float v = vv[kk];
#pragma unroll
            for (int s = 0; s < 4; ++s) {
                float4 wv4 = *(const float4*)&wkl[r * 16 + ((s ^ f) << 2)];
                acc[s * 4 + 0] = fmaf(v, wv4.x, acc[s * 4 + 0]);
                acc[s * 4 + 1] = fmaf(v, wv4.y, acc[s * 4 + 1]);
                acc[s * 4 + 2] = fmaf(v, wv4.z, acc[s * 4 + 2]);
                acc[s * 4 + 3] = fmaf(v, wv4.w, acc[s * 4 + 3]);
            }
        }
        unsigned int pk[8];
#pragma unroll
        for (int i = 0; i < 8; ++i)
            pk[i] = ((unsigned int)f2bf(acc[2 * i + 1]) << 16) | f2bf(acc[2 * i]);
        int cx = lane ^ (p & 7);
        *(uint4*)&aggL[p * 2048 + cx * 16]        = make_uint4(pk[0], pk[1], pk[2], pk[3]);
        *(uint4*)&aggL[p * 2048 + 1024 + cx * 16] = make_uint4(pk[4], pk[5], pk[6], pk[7]);
    }
    __syncthreads();

    // ------------ phase 3: C[16 p][16 o] per wave via MFMA, K = 1024
    f32x4 cacc = {0.0f, 0.0f, 0.0f, 0.0f};
    {
        int p_ = lane & 15, oct = lane >> 4;
        int h = oct & 1, chalf = oct >> 1;
        int pbase = p_ * 2048 + h * 1024;
        int px = p_ & 7;
#pragma unroll 4
        for (int ks = 0; ks < 32; ++ks) {
            int c = ks * 2 + chalf;
            bf16x8 av = *(const bf16x8*)&aggL[pbase + ((c ^ px) << 4)];
            bf16x8 bv = *(const bf16x8*)&bfrag[(ks * 4 + wid) * 64 + lane];
            cacc = __builtin_amdgcn_mfma_f32_16x16x32_bf16(av, bv, cacc, 0, 0, 0);
        }
    }
    __syncthreads();                    // wkl region dead -> reuse for C transpose
    float* cout = wkl;                  // [64 o][17 p] fp32
    {
        int o = wid * 16 + (lane & 15);
        int rbase = (lane >> 4) * 4;    // C/D row = (lane>>4)*4 + reg   [m89]
#pragma unroll
        for (int reg = 0; reg < 4; ++reg)
            cout[o * 17 + rbase + reg] = cacc[reg];
    }
    __syncthreads();
    {
        int oo = tid >> 2, pq = tid & 3;
        float bias = linb[oo];
        float res[4];
#pragma unroll
        for (int e = 0; e < 4; ++e) {
            float s = cout[oo * 17 + pq * 4 + e] + bias;
            res[e] = s > 0.0f ? s : 0.1f * s;
        }
        *(float4*)&out[((size_t)(b * 64 + oo)) * NP + n0 + pq * 4] =
            make_float4(res[0], res[1], res[2], res[3]);
    }
}

extern "C" void kernel_launch(void* const* d_in, const int* in_sizes, int n_in,
                              void* d_out, int out_size, void* d_ws, size_t ws_size,
                              hipStream_t stream) {
    const float* xyz  = (const float*)d_in[0];
    const float* pts  = (const float*)d_in[1];
    const float* w0   = (const float*)d_in[2];
    const float* b0   = (const float*)d_in[3];
    const float* w1   = (const float*)d_in[4];
    const float* b1   = (const float*)d_in[5];
    const float* w2   = (const float*)d_in[6];
    const float* b2   = (const float*)d_in[7];
    const float* lw   = (const float*)d_in[8];
    const float* linb = (const float*)d_in[9];
    float* out = (float*)d_out;

    char* ws = (char*)d_ws;
    float4* xyzt  = (float4*)(ws + OFF_XYZT);
    int*    idx   = (int*)(ws + OFF_IDX);
    float*  ptst  = (float*)(ws + OFF_PTST);
    uint4*  bfrag = (uint4*)(ws + OFF_BFRAG);

    k_prep_xyz<<<128, 256, 0, stream>>>(xyz, xyzt);
    k_knn<<<784, 512, 0, stream>>>(xyzt, idx, pts, lw, ptst, bfrag);
    k_wagg<<<BN / 16, 256, 0, stream>>>(xyzt, idx, ptst, bfrag,
                                        w0, b0, w1, b1, w2, b2, linb, out);
    (void)in_sizes; (void)n_in; (void)out_size; (void)ws_size;
}